// Round 1
// baseline (868.590 us; speedup 1.0000x reference)
//
#include <hip/hip_runtime.h>
#include <math.h>

#define DIMD 768
#define DSTATE 64
#define DCONV 4
#define DINNER 1536
#define DTRANK 48
#define BATCH 2
#define SEQL 1024
#define NTOK (BATCH*SEQL)
#define XDBL_W (DTRANK + 2*DSTATE)   // 176
#define EPSV 1e-5f

// ---------------- LayerNorm: one wave per row of 768 ----------------
__global__ __launch_bounds__(256) void ln_kernel(const float* __restrict__ x,
                                                 const float* __restrict__ gamma,
                                                 const float* __restrict__ beta,
                                                 float* __restrict__ xn) {
  int wave = threadIdx.x >> 6;
  int lane = threadIdx.x & 63;
  int row = blockIdx.x * 4 + wave;
  if (row >= NTOK) return;
  const float* xr = x + (size_t)row * DIMD;
  float v[12];
  float s = 0.f, ss = 0.f;
#pragma unroll
  for (int i = 0; i < 12; ++i) {
    v[i] = xr[lane + i*64];
    s += v[i];
    ss += v[i]*v[i];
  }
#pragma unroll
  for (int m = 1; m < 64; m <<= 1) {
    s  += __shfl_xor(s, m);
    ss += __shfl_xor(ss, m);
  }
  float mu   = s * (1.f/DIMD);
  float var  = ss * (1.f/DIMD) - mu*mu;
  float rstd = rsqrtf(var + EPSV);
  float* o = xn + (size_t)row * DIMD;
#pragma unroll
  for (int i = 0; i < 12; ++i) {
    int j = lane + i*64;
    o[j] = (v[i] - mu) * rstd * gamma[j] + beta[j];
  }
}

// ---------------- Generic fp32 NT GEMM: C = act(A @ W^T + bias) ----------------
// A: [M,K] row-major (lda), W: [N,K] row-major (ldw), C: [M,N] (ldc)
// BM=BN=64, BK=16, 256 threads, 4x4 per thread. ACT: 0=none, 1=bias+softplus
template<int ACT>
__global__ __launch_bounds__(256) void gemm_nt(const float* __restrict__ A, int lda,
                                               const float* __restrict__ W, int ldw,
                                               const float* __restrict__ bias,
                                               float* __restrict__ C, int ldc,
                                               int M, int N, int K) {
  __shared__ float As[16][68];   // [k][m], row stride 68 keeps float4 alignment
  __shared__ float Ws[16][68];   // [k][n]
  int tid = threadIdx.x;
  int m0 = blockIdx.y * 64;
  int n0 = blockIdx.x * 64;
  int lrow = tid >> 2;   // 0..63
  int lq   = tid & 3;    // k-quad
  int tx = tid & 15;
  int ty = tid >> 4;     // 0..15
  float acc[4][4] = {{0.f}};

  for (int k0 = 0; k0 < K; k0 += 16) {
    float4 av = make_float4(0.f,0.f,0.f,0.f);
    int ar = m0 + lrow;
    if (ar < M) av = *(const float4*)(A + (size_t)ar*lda + k0 + lq*4);
    float4 wv = make_float4(0.f,0.f,0.f,0.f);
    int wr = n0 + lrow;
    if (wr < N) wv = *(const float4*)(W + (size_t)wr*ldw + k0 + lq*4);
    __syncthreads();
    As[lq*4+0][lrow] = av.x; As[lq*4+1][lrow] = av.y;
    As[lq*4+2][lrow] = av.z; As[lq*4+3][lrow] = av.w;
    Ws[lq*4+0][lrow] = wv.x; Ws[lq*4+1][lrow] = wv.y;
    Ws[lq*4+2][lrow] = wv.z; Ws[lq*4+3][lrow] = wv.w;
    __syncthreads();
#pragma unroll
    for (int kk = 0; kk < 16; ++kk) {
      float4 a4 = *(const float4*)&As[kk][ty*4];
      float4 w4 = *(const float4*)&Ws[kk][tx*4];
      float a[4] = {a4.x, a4.y, a4.z, a4.w};
      float w[4] = {w4.x, w4.y, w4.z, w4.w};
#pragma unroll
      for (int i = 0; i < 4; ++i)
#pragma unroll
        for (int j = 0; j < 4; ++j)
          acc[i][j] += a[i]*w[j];
    }
  }

#pragma unroll
  for (int i = 0; i < 4; ++i) {
    int m = m0 + ty*4 + i;
    if (m >= M) continue;
    float* crow = C + (size_t)m*ldc;
#pragma unroll
    for (int j = 0; j < 4; ++j) {
      int n = n0 + tx*4 + j;
      if (n >= N) continue;
      float val = acc[i][j];
      if (ACT == 1) {
        val += bias[n];
        val = (val > 20.f) ? val : log1pf(__expf(val));  // softplus
      }
      crow[n] = val;
    }
  }
}

// ---------------- Causal depthwise conv(4) + SiLU ----------------
// u_pre lives in xz[..., 0:DINNER] (row stride 2*DINNER)
__global__ __launch_bounds__(256) void conv_silu_kernel(const float* __restrict__ xz,
                                                        const float* __restrict__ conv_w,
                                                        const float* __restrict__ conv_b,
                                                        float* __restrict__ uc) {
  int idx = blockIdx.x * 256 + threadIdx.x;      // over NTOK*DINNER
  int c  = idx % DINNER;
  int bl = idx / DINNER;
  int l  = bl % SEQL;
  const int S = 2*DINNER;
  const float* up = xz + (size_t)bl * S + c;
  float w0 = conv_w[c*4+0], w1 = conv_w[c*4+1], w2 = conv_w[c*4+2], w3 = conv_w[c*4+3];
  float acc = conv_b[c];
  if (l >= 3) acc += up[-3*S] * w0;
  if (l >= 2) acc += up[-2*S] * w1;
  if (l >= 1) acc += up[-1*S] * w2;
  acc += up[0] * w3;
  float sig = 1.f / (1.f + __expf(-acc));
  uc[idx] = acc * sig;
}

// ---------------- Selective scan: one wave per (b, channel), lane = state ----------------
__global__ __launch_bounds__(256) void scan_kernel(const float* __restrict__ delta,  // [NTOK][DINNER]
                                                   const float* __restrict__ x_dbl,  // [NTOK][176]
                                                   const float* __restrict__ uconv,  // [NTOK][DINNER]
                                                   const float* __restrict__ A_log,  // [DINNER][64]
                                                   const float* __restrict__ Dp,     // [DINNER]
                                                   float* __restrict__ yT) {         // [BATCH][DINNER][SEQL]
  int wave = threadIdx.x >> 6;
  int lane = threadIdx.x & 63;
  int ch = blockIdx.x * 4 + wave;   // 0..BATCH*DINNER-1
  int b = ch / DINNER;
  int c = ch % DINNER;
  float Ac = -__expf(A_log[(size_t)c*64 + lane]);
  float Dc = Dp[c];
  float h = 0.f, ykeep = 0.f;
  size_t tok0 = (size_t)b * SEQL;
  float* yrow = yT + ((size_t)b*DINNER + c) * SEQL;
  for (int t = 0; t < SEQL; ++t) {
    size_t tok = tok0 + t;
    float d = delta[tok*DINNER + c];
    float u = uconv[tok*DINNER + c];
    const float* xd = x_dbl + tok*XDBL_W;
    float Bv = xd[DTRANK + lane];
    float Cv = xd[DTRANK + DSTATE + lane];
    float dA = __expf(d * Ac);
    h = dA*h + (d*u)*Bv;
    float acc = h * Cv;
#pragma unroll
    for (int m = 1; m < 64; m <<= 1) acc += __shfl_xor(acc, m);
    float y = acc + Dc * u;
    if ((t & 63) == lane) ykeep = y;
    if ((t & 63) == 63) yrow[(t & ~63) + lane] = ykeep;
  }
}

// ---------------- gate: g[b,t,c] = yT[b,c,t] * silu(z[b,t,c]) (LDS transpose) ----------------
__global__ __launch_bounds__(256) void ymul_kernel(const float* __restrict__ yT,
                                                   const float* __restrict__ xz,
                                                   float* __restrict__ g) {
  __shared__ float tile[64][65];
  int b  = blockIdx.z;
  int c0 = blockIdx.x * 64;
  int t0 = blockIdx.y * 64;
  int lx = threadIdx.x & 63;
  int ly = threadIdx.x >> 6;   // 0..3
  const float* src = yT + ((size_t)b*DINNER + c0) * SEQL + t0;
#pragma unroll
  for (int i = 0; i < 16; ++i) {
    int c = ly*16 + i;
    tile[c][lx] = src[(size_t)c*SEQL + lx];   // coalesced along t
  }
  __syncthreads();
  const int S = 2*DINNER;
#pragma unroll
  for (int i = 0; i < 16; ++i) {
    int t = ly*16 + i;
    float z = xz[((size_t)b*SEQL + t0 + t)*S + DINNER + c0 + lx];
    float zs = z / (1.f + __expf(-z));
    g[((size_t)b*SEQL + t0 + t)*DINNER + c0 + lx] = tile[lx][t] * zs;
  }
}

extern "C" void kernel_launch(void* const* d_in, const int* in_sizes, int n_in,
                              void* d_out, int out_size, void* d_ws, size_t ws_size,
                              hipStream_t stream) {
  const float* x      = (const float*)d_in[0];
  const float* gamma  = (const float*)d_in[1];
  const float* beta   = (const float*)d_in[2];
  const float* W_in   = (const float*)d_in[3];
  const float* conv_w = (const float*)d_in[4];
  const float* conv_b = (const float*)d_in[5];
  const float* W_x    = (const float*)d_in[6];
  const float* W_dt   = (const float*)d_in[7];
  const float* b_dt   = (const float*)d_in[8];
  const float* A_log  = (const float*)d_in[9];
  const float* Dvec   = (const float*)d_in[10];
  const float* W_out  = (const float*)d_in[11];
  float* out = (float*)d_out;

  float* ws = (float*)d_ws;
  float* xn   = ws;                                 // NTOK*DIMD
  float* xz   = xn   + (size_t)NTOK*DIMD;           // NTOK*2*DINNER
  float* uc   = xz   + (size_t)NTOK*2*DINNER;       // NTOK*DINNER
  float* xdbl = uc   + (size_t)NTOK*DINNER;         // NTOK*176
  float* dlt  = xdbl + (size_t)NTOK*XDBL_W;         // NTOK*DINNER (reused as g)
  float* yT   = dlt  + (size_t)NTOK*DINNER;         // NTOK*DINNER

  // 1. LayerNorm
  ln_kernel<<<NTOK/4, 256, 0, stream>>>(x, gamma, beta, xn);
  // 2. xz = xn @ W_in^T   [2048 x 3072]
  gemm_nt<0><<<dim3(48, 32), 256, 0, stream>>>(xn, DIMD, W_in, DIMD, nullptr,
                                               xz, 2*DINNER, NTOK, 2*DINNER, DIMD);
  // 3. causal conv + silu  -> uc [2048 x 1536]
  conv_silu_kernel<<<(NTOK*DINNER)/256, 256, 0, stream>>>(xz, conv_w, conv_b, uc);
  // 4. x_dbl = uc @ W_x^T  [2048 x 176]
  gemm_nt<0><<<dim3(3, 32), 256, 0, stream>>>(uc, DINNER, W_x, DINNER, nullptr,
                                              xdbl, XDBL_W, NTOK, XDBL_W, DINNER);
  // 5. delta = softplus(dt @ W_dt^T + b_dt)  [2048 x 1536]
  gemm_nt<1><<<dim3(24, 32), 256, 0, stream>>>(xdbl, XDBL_W, W_dt, DTRANK, b_dt,
                                               dlt, DINNER, NTOK, DINNER, DTRANK);
  // 6. selective scan -> yT [B][DINNER][SEQL]
  scan_kernel<<<(BATCH*DINNER)/4, 256, 0, stream>>>(dlt, xdbl, uc, A_log, Dvec, yT);
  // 7. gate: g = yT^T * silu(z)  (overwrites dlt)
  ymul_kernel<<<dim3(DINNER/64, SEQL/64, BATCH), 256, 0, stream>>>(yT, xz, dlt);
  // 8. out = g @ W_out^T  [2048 x 768]
  gemm_nt<0><<<dim3(12, 32), 256, 0, stream>>>(dlt, DINNER, W_out, DINNER, nullptr,
                                               out, DIMD, NTOK, DIMD, DINNER);
}

// Round 2
// 466.621 us; speedup vs baseline: 1.8614x; 1.8614x over previous
//
#include <hip/hip_runtime.h>
#include <math.h>

#define DIMD 768
#define DSTATE 64
#define DCONV 4
#define DINNER 1536
#define DTRANK 48
#define BATCH 2
#define SEQL 1024
#define NTOK (BATCH*SEQL)
#define XDBL_W (DTRANK + 2*DSTATE)   // 176
#define EPSV 1e-5f

// ---------------- LayerNorm: one wave per row of 768 ----------------
__global__ __launch_bounds__(256) void ln_kernel(const float* __restrict__ x,
                                                 const float* __restrict__ gamma,
                                                 const float* __restrict__ beta,
                                                 float* __restrict__ xn) {
  int wave = threadIdx.x >> 6;
  int lane = threadIdx.x & 63;
  int row = blockIdx.x * 4 + wave;
  if (row >= NTOK) return;
  const float* xr = x + (size_t)row * DIMD;
  float v[12];
  float s = 0.f, ss = 0.f;
#pragma unroll
  for (int i = 0; i < 12; ++i) {
    v[i] = xr[lane + i*64];
    s += v[i];
    ss += v[i]*v[i];
  }
#pragma unroll
  for (int m = 1; m < 64; m <<= 1) {
    s  += __shfl_xor(s, m);
    ss += __shfl_xor(ss, m);
  }
  float mu   = s * (1.f/DIMD);
  float var  = ss * (1.f/DIMD) - mu*mu;
  float rstd = rsqrtf(var + EPSV);
  float* o = xn + (size_t)row * DIMD;
#pragma unroll
  for (int i = 0; i < 12; ++i) {
    int j = lane + i*64;
    o[j] = (v[i] - mu) * rstd * gamma[j] + beta[j];
  }
}

// ---------------- Generic fp32 NT GEMM: C = act(A @ W^T + bias) ----------------
template<int ACT>
__global__ __launch_bounds__(256) void gemm_nt(const float* __restrict__ A, int lda,
                                               const float* __restrict__ W, int ldw,
                                               const float* __restrict__ bias,
                                               float* __restrict__ C, int ldc,
                                               int M, int N, int K) {
  __shared__ float As[16][68];
  __shared__ float Ws[16][68];
  int tid = threadIdx.x;
  int m0 = blockIdx.y * 64;
  int n0 = blockIdx.x * 64;
  int lrow = tid >> 2;
  int lq   = tid & 3;
  int tx = tid & 15;
  int ty = tid >> 4;
  float acc[4][4] = {{0.f}};

  for (int k0 = 0; k0 < K; k0 += 16) {
    float4 av = make_float4(0.f,0.f,0.f,0.f);
    int ar = m0 + lrow;
    if (ar < M) av = *(const float4*)(A + (size_t)ar*lda + k0 + lq*4);
    float4 wv = make_float4(0.f,0.f,0.f,0.f);
    int wr = n0 + lrow;
    if (wr < N) wv = *(const float4*)(W + (size_t)wr*ldw + k0 + lq*4);
    __syncthreads();
    As[lq*4+0][lrow] = av.x; As[lq*4+1][lrow] = av.y;
    As[lq*4+2][lrow] = av.z; As[lq*4+3][lrow] = av.w;
    Ws[lq*4+0][lrow] = wv.x; Ws[lq*4+1][lrow] = wv.y;
    Ws[lq*4+2][lrow] = wv.z; Ws[lq*4+3][lrow] = wv.w;
    __syncthreads();
#pragma unroll
    for (int kk = 0; kk < 16; ++kk) {
      float4 a4 = *(const float4*)&As[kk][ty*4];
      float4 w4 = *(const float4*)&Ws[kk][tx*4];
      float a[4] = {a4.x, a4.y, a4.z, a4.w};
      float w[4] = {w4.x, w4.y, w4.z, w4.w};
#pragma unroll
      for (int i = 0; i < 4; ++i)
#pragma unroll
        for (int j = 0; j < 4; ++j)
          acc[i][j] += a[i]*w[j];
    }
  }

#pragma unroll
  for (int i = 0; i < 4; ++i) {
    int m = m0 + ty*4 + i;
    if (m >= M) continue;
    float* crow = C + (size_t)m*ldc;
#pragma unroll
    for (int j = 0; j < 4; ++j) {
      int n = n0 + tx*4 + j;
      if (n >= N) continue;
      float val = acc[i][j];
      if (ACT == 1) {
        val += bias[n];
        val = (val > 20.f) ? val : log1pf(__expf(val));
      }
      crow[n] = val;
    }
  }
}

// ---------------- Causal depthwise conv(4) + SiLU ----------------
__global__ __launch_bounds__(256) void conv_silu_kernel(const float* __restrict__ xz,
                                                        const float* __restrict__ conv_w,
                                                        const float* __restrict__ conv_b,
                                                        float* __restrict__ uc) {
  int idx = blockIdx.x * 256 + threadIdx.x;
  int c  = idx % DINNER;
  int bl = idx / DINNER;
  int l  = bl % SEQL;
  const int S = 2*DINNER;
  const float* up = xz + (size_t)bl * S + c;
  float w0 = conv_w[c*4+0], w1 = conv_w[c*4+1], w2 = conv_w[c*4+2], w3 = conv_w[c*4+3];
  float acc = conv_b[c];
  if (l >= 3) acc += up[-3*S] * w0;
  if (l >= 2) acc += up[-2*S] * w1;
  if (l >= 1) acc += up[-1*S] * w2;
  acc += up[0] * w3;
  float sig = 1.f / (1.f + __expf(-acc));
  uc[idx] = acc * sig;
}

__device__ inline float readlane_f(float v, int l) {
  return __int_as_float(__builtin_amdgcn_readlane(__float_as_int(v), l));
}

// ---------------- Selective scan v2: one wave (block) per (b, channel) ----------------
// lane = state. Per 64-token block: batch-load d/u (lane=t), readlane broadcast,
// prefetched B/C groups, LDS transpose-reduce every 32 steps.
__global__ __launch_bounds__(64) void scan_kernel(const float* __restrict__ delta,  // [NTOK][DINNER]
                                                  const float* __restrict__ x_dbl,  // [NTOK][176]
                                                  const float* __restrict__ uconv,  // [NTOK][DINNER]
                                                  const float* __restrict__ A_log,  // [DINNER][64]
                                                  const float* __restrict__ Dp,     // [DINNER]
                                                  float* __restrict__ yT) {         // [BATCH][DINNER][SEQL]
  __shared__ float red[32*65 + 32];   // [t_local][n], stride 65 -> conflict-free
  int lane = threadIdx.x;
  int ch = blockIdx.x;
  int b = ch / DINNER;
  int c = ch % DINNER;
  float Ac = -__expf(A_log[(size_t)c*64 + lane]);
  float Dc = Dp[c];
  float h = 0.f;
  size_t tokbase = (size_t)b * SEQL;
  float* yrow = yT + ((size_t)b*DINNER + c) * SEQL;

  // preload block 0 d/u
  float d_v = delta[(tokbase + lane)*DINNER + c];
  float u_v = uconv[(tokbase + lane)*DINNER + c];

  const int NBLK = SEQL/64;
  for (int blk = 0; blk < NBLK; ++blk) {
    int t0 = blk*64;
    // prefetch next block's d/u early
    float d_nxt = 0.f, u_nxt = 0.f;
    if (blk + 1 < NBLK) {
      size_t tok2 = tokbase + t0 + 64 + lane;
      d_nxt = delta[tok2*DINNER + c];
      u_nxt = uconv[tok2*DINNER + c];
    }
    float du_v = d_v * u_v;

#pragma unroll
    for (int half = 0; half < 2; ++half) {
      const float* xh = x_dbl + (tokbase + t0 + half*32)*XDBL_W + DTRANK + lane;
      float bb[8], cc[8];
#pragma unroll
      for (int k = 0; k < 8; ++k) {
        bb[k] = xh[k*XDBL_W];
        cc[k] = xh[k*XDBL_W + DSTATE];
      }
#pragma unroll
      for (int g = 0; g < 4; ++g) {
        float nb[8], nc[8];
        if (g < 3) {
          const float* x2 = xh + (g+1)*8*XDBL_W;
#pragma unroll
          for (int k = 0; k < 8; ++k) {
            nb[k] = x2[k*XDBL_W];
            nc[k] = x2[k*XDBL_W + DSTATE];
          }
        }
#pragma unroll
        for (int k = 0; k < 8; ++k) {
          int i = half*32 + g*8 + k;       // compile-time after unroll
          float sd  = readlane_f(d_v,  i);
          float sdu = readlane_f(du_v, i);
          float dA = __expf(sd * Ac);
          h = fmaf(dA, h, sdu * bb[k]);
          red[(g*8 + k)*65 + lane] = h * cc[k];
        }
        if (g < 3) {
#pragma unroll
          for (int k = 0; k < 8; ++k) { bb[k] = nb[k]; cc[k] = nc[k]; }
        }
      }
      __syncthreads();   // writes visible (single wave: waitcnt+barrier, cheap)
      int r  = lane & 31;
      int hs = lane >> 5;
      float y = 0.f;
#pragma unroll
      for (int j = 0; j < 32; ++j) y += red[r*65 + hs*32 + j];
      y += __shfl_xor(y, 32);
      float ut = __shfl(u_v, half*32 + r);
      y = fmaf(Dc, ut, y);
      if (lane < 32) yrow[t0 + half*32 + lane] = y;
      __syncthreads();   // guard LDS reuse for next half
    }
    d_v = d_nxt;
    u_v = u_nxt;
  }
}

// ---------------- gate: g[b,t,c] = yT[b,c,t] * silu(z[b,t,c]) ----------------
__global__ __launch_bounds__(256) void ymul_kernel(const float* __restrict__ yT,
                                                   const float* __restrict__ xz,
                                                   float* __restrict__ g) {
  __shared__ float tile[64][65];
  int b  = blockIdx.z;
  int c0 = blockIdx.x * 64;
  int t0 = blockIdx.y * 64;
  int lx = threadIdx.x & 63;
  int ly = threadIdx.x >> 6;
  const float* src = yT + ((size_t)b*DINNER + c0) * SEQL + t0;
#pragma unroll
  for (int i = 0; i < 16; ++i) {
    int c = ly*16 + i;
    tile[c][lx] = src[(size_t)c*SEQL + lx];
  }
  __syncthreads();
  const int S = 2*DINNER;
#pragma unroll
  for (int i = 0; i < 16; ++i) {
    int t = ly*16 + i;
    float z = xz[((size_t)b*SEQL + t0 + t)*S + DINNER + c0 + lx];
    float zs = z / (1.f + __expf(-z));
    g[((size_t)b*SEQL + t0 + t)*DINNER + c0 + lx] = tile[lx][t] * zs;
  }
}

extern "C" void kernel_launch(void* const* d_in, const int* in_sizes, int n_in,
                              void* d_out, int out_size, void* d_ws, size_t ws_size,
                              hipStream_t stream) {
  const float* x      = (const float*)d_in[0];
  const float* gamma  = (const float*)d_in[1];
  const float* beta   = (const float*)d_in[2];
  const float* W_in   = (const float*)d_in[3];
  const float* conv_w = (const float*)d_in[4];
  const float* conv_b = (const float*)d_in[5];
  const float* W_x    = (const float*)d_in[6];
  const float* W_dt   = (const float*)d_in[7];
  const float* b_dt   = (const float*)d_in[8];
  const float* A_log  = (const float*)d_in[9];
  const float* Dvec   = (const float*)d_in[10];
  const float* W_out  = (const float*)d_in[11];
  float* out = (float*)d_out;

  float* ws = (float*)d_ws;
  float* xn   = ws;
  float* xz   = xn   + (size_t)NTOK*DIMD;
  float* uc   = xz   + (size_t)NTOK*2*DINNER;
  float* xdbl = uc   + (size_t)NTOK*DINNER;
  float* dlt  = xdbl + (size_t)NTOK*XDBL_W;
  float* yT   = dlt  + (size_t)NTOK*DINNER;

  ln_kernel<<<NTOK/4, 256, 0, stream>>>(x, gamma, beta, xn);
  gemm_nt<0><<<dim3(48, 32), 256, 0, stream>>>(xn, DIMD, W_in, DIMD, nullptr,
                                               xz, 2*DINNER, NTOK, 2*DINNER, DIMD);
  conv_silu_kernel<<<(NTOK*DINNER)/256, 256, 0, stream>>>(xz, conv_w, conv_b, uc);
  gemm_nt<0><<<dim3(3, 32), 256, 0, stream>>>(uc, DINNER, W_x, DINNER, nullptr,
                                              xdbl, XDBL_W, NTOK, XDBL_W, DINNER);
  gemm_nt<1><<<dim3(24, 32), 256, 0, stream>>>(xdbl, XDBL_W, W_dt, DTRANK, b_dt,
                                               dlt, DINNER, NTOK, DINNER, DTRANK);
  scan_kernel<<<BATCH*DINNER, 64, 0, stream>>>(dlt, xdbl, uc, A_log, Dvec, yT);
  ymul_kernel<<<dim3(DINNER/64, SEQL/64, BATCH), 256, 0, stream>>>(yT, xz, dlt);
  gemm_nt<0><<<dim3(12, 32), 256, 0, stream>>>(dlt, DINNER, W_out, DINNER, nullptr,
                                               out, DIMD, NTOK, DIMD, DINNER);
}

// Round 3
// 242.926 us; speedup vs baseline: 3.5755x; 1.9208x over previous
//
#include <hip/hip_runtime.h>
#include <math.h>

#define DIMD 768
#define DSTATE 64
#define DINNER 1536
#define DTRANK 48
#define BATCH 2
#define SEQL 1024
#define NTOK (BATCH*SEQL)
#define XDBL_P 192              // padded x_dbl row stride (176 -> 192)
#define EPSV 1e-5f

typedef __attribute__((ext_vector_type(8))) short bf16x8;
typedef __attribute__((ext_vector_type(4))) float f32x4;

__device__ inline short f2bf(float f) {             // RTNE f32 -> bf16
  unsigned u = __float_as_uint(f);
  u = u + 0x7FFFu + ((u >> 16) & 1u);
  return (short)(u >> 16);
}

// ---------------- LayerNorm -> bf16 ----------------
__global__ __launch_bounds__(256) void ln_kernel(const float* __restrict__ x,
                                                 const float* __restrict__ gamma,
                                                 const float* __restrict__ beta,
                                                 short* __restrict__ xnq) {
  int wave = threadIdx.x >> 6;
  int lane = threadIdx.x & 63;
  int row = blockIdx.x * 4 + wave;
  if (row >= NTOK) return;
  const float* xr = x + (size_t)row * DIMD;
  float v[12];
  float s = 0.f, ss = 0.f;
#pragma unroll
  for (int i = 0; i < 12; ++i) {
    v[i] = xr[lane + i*64];
    s += v[i];
    ss += v[i]*v[i];
  }
#pragma unroll
  for (int m = 1; m < 64; m <<= 1) {
    s  += __shfl_xor(s, m);
    ss += __shfl_xor(ss, m);
  }
  float mu   = s * (1.f/DIMD);
  float var  = ss * (1.f/DIMD) - mu*mu;
  float rstd = rsqrtf(var + EPSV);
  short* o = xnq + (size_t)row * DIMD;
#pragma unroll
  for (int i = 0; i < 12; ++i) {
    int j = lane + i*64;
    o[j] = f2bf((v[i] - mu) * rstd * gamma[j] + beta[j]);
  }
}

// ---------------- weight f32->bf16 (W_x padded 176->192 rows) ----------------
#define NW_IN  (3072*768)
#define NW_OUT (768*1536)
#define NW_XP  (192*1536)
__global__ __launch_bounds__(256) void cvt_weights_kernel(const float* __restrict__ Win,
                                                          const float* __restrict__ Wout,
                                                          const float* __restrict__ Wx,
                                                          short* __restrict__ qin,
                                                          short* __restrict__ qout,
                                                          short* __restrict__ qx) {
  int idx = blockIdx.x * 256 + threadIdx.x;
  if (idx < NW_IN) { qin[idx] = f2bf(Win[idx]); return; }
  idx -= NW_IN;
  if (idx < NW_OUT) { qout[idx] = f2bf(Wout[idx]); return; }
  idx -= NW_OUT;
  if (idx < NW_XP) {
    int r = idx / 1536;
    qx[idx] = (r < 176) ? f2bf(Wx[idx]) : (short)0;
  }
}

// ---------------- bf16 MFMA NT GEMM: C(f32) = A(bf16,[M][K]) @ B(bf16,[N][K])^T ----------------
// BM=128, BK=64, 256 threads (4 waves). BN template: 128 (2x2 waves) or 64 (4x1 waves).
// All dims must be tile multiples (caller pads). m97 structure: global_load_lds w16, 2-barrier.
template<int BN>
__global__ __launch_bounds__(256) void gemm_mfma(const short* __restrict__ A,
                                                 const short* __restrict__ B,
                                                 float* __restrict__ C, int ldc, int K) {
  constexpr int BM = 128, BK = 64;
  constexpr int WN = (BN == 128) ? 2 : 1;
  constexpr int WM = 4 / WN;
  constexpr int MFR = BM / (WM * 16);
  constexpr int NFR = BN / (WN * 16);
  constexpr int BSW = (BN * BK * 2) / 4096;   // B staging sweeps
  __shared__ short As[BM * BK];
  __shared__ short Bs[BN * BK];
  const int tid  = threadIdx.x;
  const int wave = tid >> 6, lane = tid & 63;
  const int m0 = blockIdx.y * BM;
  const int n0 = blockIdx.x * BN;
  const int wm = wave / WN, wn = wave % WN;

  const short* aSrc = A + (size_t)(m0 + (tid >> 3)) * K + (tid & 7) * 8;
  const short* bSrc = B + (size_t)(n0 + (tid >> 3)) * K + (tid & 7) * 8;

  f32x4 acc[MFR][NFR];
#pragma unroll
  for (int i = 0; i < MFR; ++i)
#pragma unroll
    for (int j = 0; j < NFR; ++j)
      acc[i][j] = (f32x4){0.f, 0.f, 0.f, 0.f};

  for (int k0 = 0; k0 < K; k0 += BK) {
#pragma unroll
    for (int s = 0; s < 4; ++s)
      __builtin_amdgcn_global_load_lds(
        (const __attribute__((address_space(1))) void*)(aSrc + (size_t)s*32*K + k0),
        (__attribute__((address_space(3))) void*)((char*)As + s*4096 + wave*1024),
        16, 0, 0);
#pragma unroll
    for (int s = 0; s < BSW; ++s)
      __builtin_amdgcn_global_load_lds(
        (const __attribute__((address_space(1))) void*)(bSrc + (size_t)s*32*K + k0),
        (__attribute__((address_space(3))) void*)((char*)Bs + s*4096 + wave*1024),
        16, 0, 0);
    __syncthreads();   // waitcnt vmcnt(0) + barrier: tiles ready

#pragma unroll
    for (int kk = 0; kk < 2; ++kk) {
      bf16x8 af[MFR], bfr[NFR];
#pragma unroll
      for (int i = 0; i < MFR; ++i) {
        int r = wm * (BM / WM) + i * 16 + (lane & 15);
        af[i] = *(const bf16x8*)&As[r * BK + kk * 32 + (lane >> 4) * 8];
      }
#pragma unroll
      for (int j = 0; j < NFR; ++j) {
        int r = wn * (BN / WN) + j * 16 + (lane & 15);
        bfr[j] = *(const bf16x8*)&Bs[r * BK + kk * 32 + (lane >> 4) * 8];
      }
#pragma unroll
      for (int i = 0; i < MFR; ++i)
#pragma unroll
        for (int j = 0; j < NFR; ++j)
          acc[i][j] = __builtin_amdgcn_mfma_f32_16x16x32_bf16(af[i], bfr[j], acc[i][j], 0, 0, 0);
    }
    __syncthreads();   // all waves done reading before next stage
  }

  const int cn = lane & 15, cr4 = (lane >> 4) * 4;
#pragma unroll
  for (int i = 0; i < MFR; ++i)
#pragma unroll
    for (int j = 0; j < NFR; ++j)
#pragma unroll
      for (int r = 0; r < 4; ++r) {
        int m = m0 + wm * (BM / WM) + i * 16 + cr4 + r;
        int n = n0 + wn * (BN / WN) + j * 16 + cn;
        C[(size_t)m * ldc + n] = acc[i][j][r];
      }
}

// ---------------- fp32 NT GEMM (kept for small delta GEMM, K=48) ----------------
template<int ACT>
__global__ __launch_bounds__(256) void gemm_nt(const float* __restrict__ A, int lda,
                                               const float* __restrict__ W, int ldw,
                                               const float* __restrict__ bias,
                                               float* __restrict__ C, int ldc,
                                               int M, int N, int K) {
  __shared__ float Asl[16][68];
  __shared__ float Wsl[16][68];
  int tid = threadIdx.x;
  int m0 = blockIdx.y * 64;
  int n0 = blockIdx.x * 64;
  int lrow = tid >> 2;
  int lq   = tid & 3;
  int tx = tid & 15;
  int ty = tid >> 4;
  float acc[4][4] = {{0.f}};

  for (int k0 = 0; k0 < K; k0 += 16) {
    float4 av = make_float4(0.f,0.f,0.f,0.f);
    int ar = m0 + lrow;
    if (ar < M) av = *(const float4*)(A + (size_t)ar*lda + k0 + lq*4);
    float4 wv = make_float4(0.f,0.f,0.f,0.f);
    int wr = n0 + lrow;
    if (wr < N) wv = *(const float4*)(W + (size_t)wr*ldw + k0 + lq*4);
    __syncthreads();
    Asl[lq*4+0][lrow] = av.x; Asl[lq*4+1][lrow] = av.y;
    Asl[lq*4+2][lrow] = av.z; Asl[lq*4+3][lrow] = av.w;
    Wsl[lq*4+0][lrow] = wv.x; Wsl[lq*4+1][lrow] = wv.y;
    Wsl[lq*4+2][lrow] = wv.z; Wsl[lq*4+3][lrow] = wv.w;
    __syncthreads();
#pragma unroll
    for (int kk = 0; kk < 16; ++kk) {
      float4 a4 = *(const float4*)&Asl[kk][ty*4];
      float4 w4 = *(const float4*)&Wsl[kk][tx*4];
      float a[4] = {a4.x, a4.y, a4.z, a4.w};
      float w[4] = {w4.x, w4.y, w4.z, w4.w};
#pragma unroll
      for (int i = 0; i < 4; ++i)
#pragma unroll
        for (int j = 0; j < 4; ++j)
          acc[i][j] += a[i]*w[j];
    }
  }

#pragma unroll
  for (int i = 0; i < 4; ++i) {
    int m = m0 + ty*4 + i;
    if (m >= M) continue;
    float* crow = C + (size_t)m*ldc;
#pragma unroll
    for (int j = 0; j < 4; ++j) {
      int n = n0 + tx*4 + j;
      if (n >= N) continue;
      float val = acc[i][j];
      if (ACT == 1) {
        val += bias[n];
        val = (val > 20.f) ? val : log1pf(__expf(val));
      }
      crow[n] = val;
    }
  }
}

// ---------------- Causal depthwise conv(4) + SiLU -> fp32 + bf16 ----------------
__global__ __launch_bounds__(256) void conv_silu_kernel(const float* __restrict__ xz,
                                                        const float* __restrict__ conv_w,
                                                        const float* __restrict__ conv_b,
                                                        float* __restrict__ uc,
                                                        short* __restrict__ ucq) {
  int idx = blockIdx.x * 256 + threadIdx.x;
  int c  = idx % DINNER;
  int bl = idx / DINNER;
  int l  = bl % SEQL;
  const int S = 2*DINNER;
  const float* up = xz + (size_t)bl * S + c;
  float w0 = conv_w[c*4+0], w1 = conv_w[c*4+1], w2 = conv_w[c*4+2], w3 = conv_w[c*4+3];
  float acc = conv_b[c];
  if (l >= 3) acc += up[-3*S] * w0;
  if (l >= 2) acc += up[-2*S] * w1;
  if (l >= 1) acc += up[-1*S] * w2;
  acc += up[0] * w3;
  float sig = 1.f / (1.f + __expf(-acc));
  float v = acc * sig;
  uc[idx] = v;
  ucq[idx] = f2bf(v);
}

__device__ inline float readlane_f(float v, int l) {
  return __int_as_float(__builtin_amdgcn_readlane(__float_as_int(v), l));
}

// ---------------- Selective scan: one wave per (b, channel), lane = state ----------------
__global__ __launch_bounds__(64) void scan_kernel(const float* __restrict__ delta,  // [NTOK][DINNER]
                                                  const float* __restrict__ x_dbl,  // [NTOK][XDBL_P]
                                                  const float* __restrict__ uconv,  // [NTOK][DINNER]
                                                  const float* __restrict__ A_log,  // [DINNER][64]
                                                  const float* __restrict__ Dp,     // [DINNER]
                                                  float* __restrict__ yT) {         // [B][DINNER][SEQL]
  __shared__ float red[32*65 + 32];
  int lane = threadIdx.x;
  int ch = blockIdx.x;
  int b = ch / DINNER;
  int c = ch % DINNER;
  float Ac = -__expf(A_log[(size_t)c*64 + lane]);
  float Dc = Dp[c];
  float h = 0.f;
  size_t tokbase = (size_t)b * SEQL;
  float* yrow = yT + ((size_t)b*DINNER + c) * SEQL;

  float d_v = delta[(tokbase + lane)*DINNER + c];
  float u_v = uconv[(tokbase + lane)*DINNER + c];

  const int NBLK = SEQL/64;
  for (int blk = 0; blk < NBLK; ++blk) {
    int t0 = blk*64;
    float d_nxt = 0.f, u_nxt = 0.f;
    if (blk + 1 < NBLK) {
      size_t tok2 = tokbase + t0 + 64 + lane;
      d_nxt = delta[tok2*DINNER + c];
      u_nxt = uconv[tok2*DINNER + c];
    }
    float du_v = d_v * u_v;

#pragma unroll
    for (int half = 0; half < 2; ++half) {
      const float* xh = x_dbl + (tokbase + t0 + half*32)*XDBL_P + DTRANK + lane;
      float bb[8], cc[8];
#pragma unroll
      for (int k = 0; k < 8; ++k) {
        bb[k] = xh[k*XDBL_P];
        cc[k] = xh[k*XDBL_P + DSTATE];
      }
#pragma unroll
      for (int g = 0; g < 4; ++g) {
        float nb[8], nc[8];
        if (g < 3) {
          const float* x2 = xh + (g+1)*8*XDBL_P;
#pragma unroll
          for (int k = 0; k < 8; ++k) {
            nb[k] = x2[k*XDBL_P];
            nc[k] = x2[k*XDBL_P + DSTATE];
          }
        }
#pragma unroll
        for (int k = 0; k < 8; ++k) {
          int i = half*32 + g*8 + k;
          float sd  = readlane_f(d_v,  i);
          float sdu = readlane_f(du_v, i);
          float dA = __expf(sd * Ac);
          h = fmaf(dA, h, sdu * bb[k]);
          red[(g*8 + k)*65 + lane] = h * cc[k];
        }
        if (g < 3) {
#pragma unroll
          for (int k = 0; k < 8; ++k) { bb[k] = nb[k]; cc[k] = nc[k]; }
        }
      }
      __syncthreads();
      int r  = lane & 31;
      int hs = lane >> 5;
      float y = 0.f;
#pragma unroll
      for (int j = 0; j < 32; ++j) y += red[r*65 + hs*32 + j];
      y += __shfl_xor(y, 32);
      float ut = __shfl(u_v, half*32 + r);
      y = fmaf(Dc, ut, y);
      if (lane < 32) yrow[t0 + half*32 + lane] = y;
      __syncthreads();
    }
    d_v = d_nxt;
    u_v = u_nxt;
  }
}

// ---------------- gate: g[b,t,c] = yT[b,c,t] * silu(z[b,t,c]) -> bf16 ----------------
__global__ __launch_bounds__(256) void ymul_kernel(const float* __restrict__ yT,
                                                   const float* __restrict__ xz,
                                                   short* __restrict__ g) {
  __shared__ float tile[64][65];
  int b  = blockIdx.z;
  int c0 = blockIdx.x * 64;
  int t0 = blockIdx.y * 64;
  int lx = threadIdx.x & 63;
  int ly = threadIdx.x >> 6;
  const float* src = yT + ((size_t)b*DINNER + c0) * SEQL + t0;
#pragma unroll
  for (int i = 0; i < 16; ++i) {
    int c = ly*16 + i;
    tile[c][lx] = src[(size_t)c*SEQL + lx];
  }
  __syncthreads();
  const int S = 2*DINNER;
#pragma unroll
  for (int i = 0; i < 16; ++i) {
    int t = ly*16 + i;
    float z = xz[((size_t)b*SEQL + t0 + t)*S + DINNER + c0 + lx];
    float zs = z / (1.f + __expf(-z));
    g[((size_t)b*SEQL + t0 + t)*DINNER + c0 + lx] = f2bf(tile[lx][t] * zs);
  }
}

extern "C" void kernel_launch(void* const* d_in, const int* in_sizes, int n_in,
                              void* d_out, int out_size, void* d_ws, size_t ws_size,
                              hipStream_t stream) {
  const float* x      = (const float*)d_in[0];
  const float* gamma  = (const float*)d_in[1];
  const float* beta   = (const float*)d_in[2];
  const float* W_in   = (const float*)d_in[3];
  const float* conv_w = (const float*)d_in[4];
  const float* conv_b = (const float*)d_in[5];
  const float* W_x    = (const float*)d_in[6];
  const float* W_dt   = (const float*)d_in[7];
  const float* b_dt   = (const float*)d_in[8];
  const float* A_log  = (const float*)d_in[9];
  const float* Dvec   = (const float*)d_in[10];
  const float* W_out  = (const float*)d_in[11];
  float* out = (float*)d_out;

  float* ws = (float*)d_ws;
  float* xz   = ws;                                  // NTOK*3072
  float* uc   = xz   + (size_t)NTOK*3072;            // NTOK*1536
  float* xdbl = uc   + (size_t)NTOK*1536;            // NTOK*192
  float* dlt  = xdbl + (size_t)NTOK*XDBL_P;          // NTOK*1536
  float* yT   = dlt  + (size_t)NTOK*1536;            // NTOK*1536
  short* xnq  = (short*)(yT + (size_t)NTOK*1536);    // NTOK*768
  short* ucq  = xnq  + (size_t)NTOK*768;             // NTOK*1536
  short* gq   = ucq  + (size_t)NTOK*1536;            // NTOK*1536
  short* qin  = gq   + (size_t)NTOK*1536;            // 3072*768
  short* qx   = qin  + (size_t)NW_IN;                // 192*1536
  short* qout = qx   + (size_t)NW_XP;                // 768*1536

  // weight conversion (independent of LN)
  cvt_weights_kernel<<<(NW_IN+NW_OUT+NW_XP+255)/256, 256, 0, stream>>>(W_in, W_out, W_x, qin, qout, qx);
  // 1. LayerNorm -> bf16
  ln_kernel<<<NTOK/4, 256, 0, stream>>>(x, gamma, beta, xnq);
  // 2. xz = xn @ W_in^T  [2048 x 3072], K=768  (bf16 MFMA)
  gemm_mfma<128><<<dim3(3072/128, NTOK/128), 256, 0, stream>>>(xnq, qin, xz, 3072, DIMD);
  // 3. conv + silu -> uc (f32) + ucq (bf16)
  conv_silu_kernel<<<(NTOK*DINNER)/256, 256, 0, stream>>>(xz, conv_w, conv_b, uc, ucq);
  // 4. x_dbl = uc @ W_x^T  [2048 x 192], K=1536  (bf16 MFMA, padded N)
  gemm_mfma<64><<<dim3(XDBL_P/64, NTOK/128), 256, 0, stream>>>(ucq, qx, xdbl, XDBL_P, DINNER);
  // 5. delta = softplus(dt @ W_dt^T + b_dt)  [2048 x 1536], K=48 (fp32)
  gemm_nt<1><<<dim3(24, 32), 256, 0, stream>>>(xdbl, XDBL_P, W_dt, DTRANK, b_dt,
                                               dlt, DINNER, NTOK, DINNER, DTRANK);
  // 6. selective scan -> yT
  scan_kernel<<<BATCH*DINNER, 64, 0, stream>>>(dlt, xdbl, uc, A_log, Dvec, yT);
  // 7. gate -> gq (bf16)
  ymul_kernel<<<dim3(DINNER/64, SEQL/64, BATCH), 256, 0, stream>>>(yT, xz, gq);
  // 8. out = g @ W_out^T  [2048 x 768], K=1536  (bf16 MFMA)
  gemm_mfma<64><<<dim3(DIMD/64, NTOK/128), 256, 0, stream>>>(gq, qout, out, DIMD, DINNER);
}

// Round 4
// 230.638 us; speedup vs baseline: 3.7660x; 1.0533x over previous
//
#include <hip/hip_runtime.h>
#include <math.h>

#define DIMD 768
#define DSTATE 64
#define DINNER 1536
#define DTRANK 48
#define BATCH 2
#define SEQL 1024
#define NTOK (BATCH*SEQL)
#define XDBL_P 192              // padded x_dbl row stride (176 -> 192)
#define EPSV 1e-5f

typedef __attribute__((ext_vector_type(8))) short bf16x8;
typedef __attribute__((ext_vector_type(4))) float f32x4;

__device__ inline short f2bf(float f) {             // RTNE f32 -> bf16
  unsigned u = __float_as_uint(f);
  u = u + 0x7FFFu + ((u >> 16) & 1u);
  return (short)(u >> 16);
}

// ---------------- LayerNorm -> bf16 ----------------
__global__ __launch_bounds__(256) void ln_kernel(const float* __restrict__ x,
                                                 const float* __restrict__ gamma,
                                                 const float* __restrict__ beta,
                                                 short* __restrict__ xnq) {
  int wave = threadIdx.x >> 6;
  int lane = threadIdx.x & 63;
  int row = blockIdx.x * 4 + wave;
  if (row >= NTOK) return;
  const float* xr = x + (size_t)row * DIMD;
  float v[12];
  float s = 0.f, ss = 0.f;
#pragma unroll
  for (int i = 0; i < 12; ++i) {
    v[i] = xr[lane + i*64];
    s += v[i];
    ss += v[i]*v[i];
  }
#pragma unroll
  for (int m = 1; m < 64; m <<= 1) {
    s  += __shfl_xor(s, m);
    ss += __shfl_xor(ss, m);
  }
  float mu   = s * (1.f/DIMD);
  float var  = ss * (1.f/DIMD) - mu*mu;
  float rstd = rsqrtf(var + EPSV);
  short* o = xnq + (size_t)row * DIMD;
#pragma unroll
  for (int i = 0; i < 12; ++i) {
    int j = lane + i*64;
    o[j] = f2bf((v[i] - mu) * rstd * gamma[j] + beta[j]);
  }
}

// ---------------- weight f32->bf16 (W_x padded 176->192 rows) ----------------
#define NW_IN  (3072*768)
#define NW_OUT (768*1536)
#define NW_XP  (192*1536)
__global__ __launch_bounds__(256) void cvt_weights_kernel(const float* __restrict__ Win,
                                                          const float* __restrict__ Wout,
                                                          const float* __restrict__ Wx,
                                                          short* __restrict__ qin,
                                                          short* __restrict__ qout,
                                                          short* __restrict__ qx) {
  int idx = blockIdx.x * 256 + threadIdx.x;
  if (idx < NW_IN) { qin[idx] = f2bf(Win[idx]); return; }
  idx -= NW_IN;
  if (idx < NW_OUT) { qout[idx] = f2bf(Wout[idx]); return; }
  idx -= NW_OUT;
  if (idx < NW_XP) {
    int r = idx / 1536;
    qx[idx] = (r < 176) ? f2bf(Wx[idx]) : (short)0;
  }
}

// ---------------- bf16 MFMA NT GEMM: C(f32) = A(bf16,[M][K]) @ B(bf16,[N][K])^T ----------------
template<int BN>
__global__ __launch_bounds__(256) void gemm_mfma(const short* __restrict__ A,
                                                 const short* __restrict__ B,
                                                 float* __restrict__ C, int ldc, int K) {
  constexpr int BM = 128, BK = 64;
  constexpr int WN = (BN == 128) ? 2 : 1;
  constexpr int WM = 4 / WN;
  constexpr int MFR = BM / (WM * 16);
  constexpr int NFR = BN / (WN * 16);
  constexpr int BSW = (BN * BK * 2) / 4096;
  __shared__ short As[BM * BK];
  __shared__ short Bs[BN * BK];
  const int tid  = threadIdx.x;
  const int wave = tid >> 6, lane = tid & 63;
  const int m0 = blockIdx.y * BM;
  const int n0 = blockIdx.x * BN;
  const int wm = wave / WN, wn = wave % WN;

  const short* aSrc = A + (size_t)(m0 + (tid >> 3)) * K + (tid & 7) * 8;
  const short* bSrc = B + (size_t)(n0 + (tid >> 3)) * K + (tid & 7) * 8;

  f32x4 acc[MFR][NFR];
#pragma unroll
  for (int i = 0; i < MFR; ++i)
#pragma unroll
    for (int j = 0; j < NFR; ++j)
      acc[i][j] = (f32x4){0.f, 0.f, 0.f, 0.f};

  for (int k0 = 0; k0 < K; k0 += BK) {
#pragma unroll
    for (int s = 0; s < 4; ++s)
      __builtin_amdgcn_global_load_lds(
        (const __attribute__((address_space(1))) void*)(aSrc + (size_t)s*32*K + k0),
        (__attribute__((address_space(3))) void*)((char*)As + s*4096 + wave*1024),
        16, 0, 0);
#pragma unroll
    for (int s = 0; s < BSW; ++s)
      __builtin_amdgcn_global_load_lds(
        (const __attribute__((address_space(1))) void*)(bSrc + (size_t)s*32*K + k0),
        (__attribute__((address_space(3))) void*)((char*)Bs + s*4096 + wave*1024),
        16, 0, 0);
    __syncthreads();

#pragma unroll
    for (int kk = 0; kk < 2; ++kk) {
      bf16x8 af[MFR], bfr[NFR];
#pragma unroll
      for (int i = 0; i < MFR; ++i) {
        int r = wm * (BM / WM) + i * 16 + (lane & 15);
        af[i] = *(const bf16x8*)&As[r * BK + kk * 32 + (lane >> 4) * 8];
      }
#pragma unroll
      for (int j = 0; j < NFR; ++j) {
        int r = wn * (BN / WN) + j * 16 + (lane & 15);
        bfr[j] = *(const bf16x8*)&Bs[r * BK + kk * 32 + (lane >> 4) * 8];
      }
#pragma unroll
      for (int i = 0; i < MFR; ++i)
#pragma unroll
        for (int j = 0; j < NFR; ++j)
          acc[i][j] = __builtin_amdgcn_mfma_f32_16x16x32_bf16(af[i], bfr[j], acc[i][j], 0, 0, 0);
    }
    __syncthreads();
  }

  const int cn = lane & 15, cr4 = (lane >> 4) * 4;
#pragma unroll
  for (int i = 0; i < MFR; ++i)
#pragma unroll
    for (int j = 0; j < NFR; ++j)
#pragma unroll
      for (int r = 0; r < 4; ++r) {
        int m = m0 + wm * (BM / WM) + i * 16 + cr4 + r;
        int n = n0 + wn * (BN / WN) + j * 16 + cn;
        C[(size_t)m * ldc + n] = acc[i][j][r];
      }
}

// ---------------- fp32 NT GEMM (delta GEMM, K=48) ----------------
template<int ACT>
__global__ __launch_bounds__(256) void gemm_nt(const float* __restrict__ A, int lda,
                                               const float* __restrict__ W, int ldw,
                                               const float* __restrict__ bias,
                                               float* __restrict__ C, int ldc,
                                               int M, int N, int K) {
  __shared__ float Asl[16][68];
  __shared__ float Wsl[16][68];
  int tid = threadIdx.x;
  int m0 = blockIdx.y * 64;
  int n0 = blockIdx.x * 64;
  int lrow = tid >> 2;
  int lq   = tid & 3;
  int tx = tid & 15;
  int ty = tid >> 4;
  float acc[4][4] = {{0.f}};

  for (int k0 = 0; k0 < K; k0 += 16) {
    float4 av = make_float4(0.f,0.f,0.f,0.f);
    int ar = m0 + lrow;
    if (ar < M) av = *(const float4*)(A + (size_t)ar*lda + k0 + lq*4);
    float4 wv = make_float4(0.f,0.f,0.f,0.f);
    int wr = n0 + lrow;
    if (wr < N) wv = *(const float4*)(W + (size_t)wr*ldw + k0 + lq*4);
    __syncthreads();
    Asl[lq*4+0][lrow] = av.x; Asl[lq*4+1][lrow] = av.y;
    Asl[lq*4+2][lrow] = av.z; Asl[lq*4+3][lrow] = av.w;
    Wsl[lq*4+0][lrow] = wv.x; Wsl[lq*4+1][lrow] = wv.y;
    Wsl[lq*4+2][lrow] = wv.z; Wsl[lq*4+3][lrow] = wv.w;
    __syncthreads();
#pragma unroll
    for (int kk = 0; kk < 16; ++kk) {
      float4 a4 = *(const float4*)&Asl[kk][ty*4];
      float4 w4 = *(const float4*)&Wsl[kk][tx*4];
      float a[4] = {a4.x, a4.y, a4.z, a4.w};
      float w[4] = {w4.x, w4.y, w4.z, w4.w};
#pragma unroll
      for (int i = 0; i < 4; ++i)
#pragma unroll
        for (int j = 0; j < 4; ++j)
          acc[i][j] += a[i]*w[j];
    }
  }

#pragma unroll
  for (int i = 0; i < 4; ++i) {
    int m = m0 + ty*4 + i;
    if (m >= M) continue;
    float* crow = C + (size_t)m*ldc;
#pragma unroll
    for (int j = 0; j < 4; ++j) {
      int n = n0 + tx*4 + j;
      if (n >= N) continue;
      float val = acc[i][j];
      if (ACT == 1) {
        val += bias[n];
        val = (val > 20.f) ? val : log1pf(__expf(val));
      }
      crow[n] = val;
    }
  }
}

// ---------------- Causal depthwise conv(4) + SiLU -> fp32 + bf16 ----------------
__global__ __launch_bounds__(256) void conv_silu_kernel(const float* __restrict__ xz,
                                                        const float* __restrict__ conv_w,
                                                        const float* __restrict__ conv_b,
                                                        float* __restrict__ uc,
                                                        short* __restrict__ ucq) {
  int idx = blockIdx.x * 256 + threadIdx.x;
  int c  = idx % DINNER;
  int bl = idx / DINNER;
  int l  = bl % SEQL;
  const int S = 2*DINNER;
  const float* up = xz + (size_t)bl * S + c;
  float w0 = conv_w[c*4+0], w1 = conv_w[c*4+1], w2 = conv_w[c*4+2], w3 = conv_w[c*4+3];
  float acc = conv_b[c];
  if (l >= 3) acc += up[-3*S] * w0;
  if (l >= 2) acc += up[-2*S] * w1;
  if (l >= 1) acc += up[-1*S] * w2;
  acc += up[0] * w3;
  float sig = 1.f / (1.f + __expf(-acc));
  float v = acc * sig;
  uc[idx] = v;
  ucq[idx] = f2bf(v);
}

__device__ inline float readlane_f(float v, int l) {
  return __int_as_float(__builtin_amdgcn_readlane(__float_as_int(v), l));
}

// ---------------- Selective scan v3: 4 channels per block (1 per wave) ----------------
// Per-wave private LDS reduce region -> no barriers. 16-token double-buffered B/C.
__global__ __launch_bounds__(256) void scan_kernel(const float* __restrict__ delta,  // [NTOK][DINNER]
                                                   const float* __restrict__ x_dbl,  // [NTOK][XDBL_P]
                                                   const float* __restrict__ uconv,  // [NTOK][DINNER]
                                                   const float* __restrict__ A_log,  // [DINNER][64]
                                                   const float* __restrict__ Dp,     // [DINNER]
                                                   float* __restrict__ yT) {         // [B][DINNER][SEQL]
  __shared__ float red_all[4][32*65 + 32];
  int wave = threadIdx.x >> 6;
  int lane = threadIdx.x & 63;
  float* red = red_all[wave];
  int ch = blockIdx.x * 4 + wave;
  int b = ch / DINNER;
  int c = ch % DINNER;
  float Ac = -__expf(A_log[(size_t)c*64 + lane]);
  float Dc = Dp[c];
  float h = 0.f;
  size_t tokbase = (size_t)b * SEQL;
  float* yrow = yT + ((size_t)b*DINNER + c) * SEQL;

  float d_v = delta[(tokbase + lane)*DINNER + c];
  float u_v = uconv[(tokbase + lane)*DINNER + c];

  const int NBLK = SEQL/64;
  for (int blk = 0; blk < NBLK; ++blk) {
    int t0 = blk*64;
    float d_nxt = 0.f, u_nxt = 0.f;
    if (blk + 1 < NBLK) {
      size_t tok2 = tokbase + t0 + 64 + lane;
      d_nxt = delta[tok2*DINNER + c];
      u_nxt = uconv[tok2*DINNER + c];
    }
    float du_v = d_v * u_v;
    const float* xb = x_dbl + (tokbase + t0)*XDBL_P + DTRANK + lane;

    float bb[2][16], cc[2][16];
#pragma unroll
    for (int k = 0; k < 16; ++k) {          // group 0 load
      bb[0][k] = xb[k*XDBL_P];
      cc[0][k] = xb[k*XDBL_P + DSTATE];
    }
#pragma unroll
    for (int g = 0; g < 4; ++g) {
      constexpr int CUR_MASK = 1;
      int cur = g & CUR_MASK, nxt = cur ^ 1;
      if (g < 3) {                          // prefetch next 16 tokens
        const float* xg = xb + (g+1)*16*XDBL_P;
#pragma unroll
        for (int k = 0; k < 16; ++k) {
          bb[nxt][k] = xg[k*XDBL_P];
          cc[nxt][k] = xg[k*XDBL_P + DSTATE];
        }
      }
#pragma unroll
      for (int k = 0; k < 16; ++k) {
        int i = g*16 + k;                   // compile-time after unroll
        float sd  = readlane_f(d_v,  i);
        float sdu = readlane_f(du_v, i);
        float dA = __expf(sd * Ac);
        h = fmaf(dA, h, sdu * bb[cur][k]);
        red[(i & 31)*65 + lane] = h * cc[cur][k];
      }
      if (g & 1) {                          // reduce 32 tokens
        int half = g >> 1;
        int r  = lane & 31;
        int hs = lane >> 5;
        float y = 0.f;
        const float* rp = &red[r*65 + hs*32];
#pragma unroll
        for (int j = 0; j < 32; ++j) y += rp[j];
        y += __shfl_xor(y, 32);
        float ut = __shfl(u_v, half*32 + r);
        y = fmaf(Dc, ut, y);
        if (lane < 32) yrow[t0 + half*32 + lane] = y;
      }
    }
    d_v = d_nxt;
    u_v = u_nxt;
  }
}

// ---------------- gate: g[b,t,c] = yT[b,c,t] * silu(z[b,t,c]) -> bf16 ----------------
__global__ __launch_bounds__(256) void ymul_kernel(const float* __restrict__ yT,
                                                   const float* __restrict__ xz,
                                                   short* __restrict__ g) {
  __shared__ float tile[64][65];
  int b  = blockIdx.z;
  int c0 = blockIdx.x * 64;
  int t0 = blockIdx.y * 64;
  int lx = threadIdx.x & 63;
  int ly = threadIdx.x >> 6;
  const float* src = yT + ((size_t)b*DINNER + c0) * SEQL + t0;
#pragma unroll
  for (int i = 0; i < 16; ++i) {
    int c = ly*16 + i;
    tile[c][lx] = src[(size_t)c*SEQL + lx];
  }
  __syncthreads();
  const int S = 2*DINNER;
#pragma unroll
  for (int i = 0; i < 16; ++i) {
    int t = ly*16 + i;
    float z = xz[((size_t)b*SEQL + t0 + t)*S + DINNER + c0 + lx];
    float zs = z / (1.f + __expf(-z));
    g[((size_t)b*SEQL + t0 + t)*DINNER + c0 + lx] = f2bf(tile[lx][t] * zs);
  }
}

extern "C" void kernel_launch(void* const* d_in, const int* in_sizes, int n_in,
                              void* d_out, int out_size, void* d_ws, size_t ws_size,
                              hipStream_t stream) {
  const float* x      = (const float*)d_in[0];
  const float* gamma  = (const float*)d_in[1];
  const float* beta   = (const float*)d_in[2];
  const float* W_in   = (const float*)d_in[3];
  const float* conv_w = (const float*)d_in[4];
  const float* conv_b = (const float*)d_in[5];
  const float* W_x    = (const float*)d_in[6];
  const float* W_dt   = (const float*)d_in[7];
  const float* b_dt   = (const float*)d_in[8];
  const float* A_log  = (const float*)d_in[9];
  const float* Dvec   = (const float*)d_in[10];
  const float* W_out  = (const float*)d_in[11];
  float* out = (float*)d_out;

  float* ws = (float*)d_ws;
  float* xz   = ws;                                  // NTOK*3072
  float* uc   = xz   + (size_t)NTOK*3072;            // NTOK*1536
  float* xdbl = uc   + (size_t)NTOK*1536;            // NTOK*192
  float* dlt  = xdbl + (size_t)NTOK*XDBL_P;          // NTOK*1536
  float* yT   = dlt  + (size_t)NTOK*1536;            // NTOK*1536
  short* xnq  = (short*)(yT + (size_t)NTOK*1536);    // NTOK*768
  short* ucq  = xnq  + (size_t)NTOK*768;             // NTOK*1536
  short* gq   = ucq  + (size_t)NTOK*1536;            // NTOK*1536
  short* qin  = gq   + (size_t)NTOK*1536;            // 3072*768
  short* qx   = qin  + (size_t)NW_IN;                // 192*1536
  short* qout = qx   + (size_t)NW_XP;                // 768*1536

  cvt_weights_kernel<<<(NW_IN+NW_OUT+NW_XP+255)/256, 256, 0, stream>>>(W_in, W_out, W_x, qin, qout, qx);
  ln_kernel<<<NTOK/4, 256, 0, stream>>>(x, gamma, beta, xnq);
  gemm_mfma<128><<<dim3(3072/128, NTOK/128), 256, 0, stream>>>(xnq, qin, xz, 3072, DIMD);
  conv_silu_kernel<<<(NTOK*DINNER)/256, 256, 0, stream>>>(xz, conv_w, conv_b, uc, ucq);
  gemm_mfma<64><<<dim3(XDBL_P/64, NTOK/128), 256, 0, stream>>>(ucq, qx, xdbl, XDBL_P, DINNER);
  gemm_nt<1><<<dim3(24, 32), 256, 0, stream>>>(xdbl, XDBL_P, W_dt, DTRANK, b_dt,
                                               dlt, DINNER, NTOK, DINNER, DTRANK);
  scan_kernel<<<BATCH*DINNER/4, 256, 0, stream>>>(dlt, xdbl, uc, A_log, Dvec, yT);
  ymul_kernel<<<dim3(DINNER/64, SEQL/64, BATCH), 256, 0, stream>>>(yT, xz, gq);
  gemm_mfma<64><<<dim3(DIMD/64, NTOK/128), 256, 0, stream>>>(gq, qout, out, DIMD, DINNER);
}

// Round 5
// 214.685 us; speedup vs baseline: 4.0459x; 1.0743x over previous
//
#include <hip/hip_runtime.h>
#include <math.h>

#define DIMD 768
#define DSTATE 64
#define DINNER 1536
#define DTRANK 48
#define BATCH 2
#define SEQL 1024
#define NTOK (BATCH*SEQL)
#define XDBL_P 192              // padded x_dbl row stride (176 -> 192)
#define EPSV 1e-5f

typedef __attribute__((ext_vector_type(8))) short bf16x8;
typedef __attribute__((ext_vector_type(4))) float f32x4;

__device__ inline short f2bf(float f) {             // RTNE f32 -> bf16
  unsigned u = __float_as_uint(f);
  u = u + 0x7FFFu + ((u >> 16) & 1u);
  return (short)(u >> 16);
}

// ---------------- LayerNorm -> bf16 ----------------
__global__ __launch_bounds__(256) void ln_kernel(const float* __restrict__ x,
                                                 const float* __restrict__ gamma,
                                                 const float* __restrict__ beta,
                                                 short* __restrict__ xnq) {
  int wave = threadIdx.x >> 6;
  int lane = threadIdx.x & 63;
  int row = blockIdx.x * 4 + wave;
  if (row >= NTOK) return;
  const float* xr = x + (size_t)row * DIMD;
  float v[12];
  float s = 0.f, ss = 0.f;
#pragma unroll
  for (int i = 0; i < 12; ++i) {
    v[i] = xr[lane + i*64];
    s += v[i];
    ss += v[i]*v[i];
  }
#pragma unroll
  for (int m = 1; m < 64; m <<= 1) {
    s  += __shfl_xor(s, m);
    ss += __shfl_xor(ss, m);
  }
  float mu   = s * (1.f/DIMD);
  float var  = ss * (1.f/DIMD) - mu*mu;
  float rstd = rsqrtf(var + EPSV);
  short* o = xnq + (size_t)row * DIMD;
#pragma unroll
  for (int i = 0; i < 12; ++i) {
    int j = lane + i*64;
    o[j] = f2bf((v[i] - mu) * rstd * gamma[j] + beta[j]);
  }
}

// ---------------- weight f32->bf16 (W_x padded 176->192 rows) ----------------
#define NW_IN  (3072*768)
#define NW_OUT (768*1536)
#define NW_XP  (192*1536)
__global__ __launch_bounds__(256) void cvt_weights_kernel(const float* __restrict__ Win,
                                                          const float* __restrict__ Wout,
                                                          const float* __restrict__ Wx,
                                                          short* __restrict__ qin,
                                                          short* __restrict__ qout,
                                                          short* __restrict__ qx) {
  int idx = blockIdx.x * 256 + threadIdx.x;
  if (idx < NW_IN) { qin[idx] = f2bf(Win[idx]); return; }
  idx -= NW_IN;
  if (idx < NW_OUT) { qout[idx] = f2bf(Wout[idx]); return; }
  idx -= NW_OUT;
  if (idx < NW_XP) {
    int r = idx / 1536;
    qx[idx] = (r < 176) ? f2bf(Wx[idx]) : (short)0;
  }
}

// ---------------- bf16 MFMA NT GEMM: C(f32) = A(bf16,[M][K]) @ B(bf16,[N][K])^T ----------------
template<int BN>
__global__ __launch_bounds__(256) void gemm_mfma(const short* __restrict__ A,
                                                 const short* __restrict__ B,
                                                 float* __restrict__ C, int ldc, int K) {
  constexpr int BM = 128, BK = 64;
  constexpr int WN = (BN == 128) ? 2 : 1;
  constexpr int WM = 4 / WN;
  constexpr int MFR = BM / (WM * 16);
  constexpr int NFR = BN / (WN * 16);
  constexpr int BSW = (BN * BK * 2) / 4096;
  __shared__ short As[BM * BK];
  __shared__ short Bs[BN * BK];
  const int tid  = threadIdx.x;
  const int wave = tid >> 6, lane = tid & 63;
  const int m0 = blockIdx.y * BM;
  const int n0 = blockIdx.x * BN;
  const int wm = wave / WN, wn = wave % WN;

  const short* aSrc = A + (size_t)(m0 + (tid >> 3)) * K + (tid & 7) * 8;
  const short* bSrc = B + (size_t)(n0 + (tid >> 3)) * K + (tid & 7) * 8;

  f32x4 acc[MFR][NFR];
#pragma unroll
  for (int i = 0; i < MFR; ++i)
#pragma unroll
    for (int j = 0; j < NFR; ++j)
      acc[i][j] = (f32x4){0.f, 0.f, 0.f, 0.f};

  for (int k0 = 0; k0 < K; k0 += BK) {
#pragma unroll
    for (int s = 0; s < 4; ++s)
      __builtin_amdgcn_global_load_lds(
        (const __attribute__((address_space(1))) void*)(aSrc + (size_t)s*32*K + k0),
        (__attribute__((address_space(3))) void*)((char*)As + s*4096 + wave*1024),
        16, 0, 0);
#pragma unroll
    for (int s = 0; s < BSW; ++s)
      __builtin_amdgcn_global_load_lds(
        (const __attribute__((address_space(1))) void*)(bSrc + (size_t)s*32*K + k0),
        (__attribute__((address_space(3))) void*)((char*)Bs + s*4096 + wave*1024),
        16, 0, 0);
    __syncthreads();

#pragma unroll
    for (int kk = 0; kk < 2; ++kk) {
      bf16x8 af[MFR], bfr[NFR];
#pragma unroll
      for (int i = 0; i < MFR; ++i) {
        int r = wm * (BM / WM) + i * 16 + (lane & 15);
        af[i] = *(const bf16x8*)&As[r * BK + kk * 32 + (lane >> 4) * 8];
      }
#pragma unroll
      for (int j = 0; j < NFR; ++j) {
        int r = wn * (BN / WN) + j * 16 + (lane & 15);
        bfr[j] = *(const bf16x8*)&Bs[r * BK + kk * 32 + (lane >> 4) * 8];
      }
#pragma unroll
      for (int i = 0; i < MFR; ++i)
#pragma unroll
        for (int j = 0; j < NFR; ++j)
          acc[i][j] = __builtin_amdgcn_mfma_f32_16x16x32_bf16(af[i], bfr[j], acc[i][j], 0, 0, 0);
    }
    __syncthreads();
  }

  const int cn = lane & 15, cr4 = (lane >> 4) * 4;
#pragma unroll
  for (int i = 0; i < MFR; ++i)
#pragma unroll
    for (int j = 0; j < NFR; ++j)
#pragma unroll
      for (int r = 0; r < 4; ++r) {
        int m = m0 + wm * (BM / WM) + i * 16 + cr4 + r;
        int n = n0 + wn * (BN / WN) + j * 16 + cn;
        C[(size_t)m * ldc + n] = acc[i][j][r];
      }
}

// ---------------- fp32 NT GEMM. ACT: 0 none, 2 = bias[m]+softplus (row bias) ----------------
template<int ACT>
__global__ __launch_bounds__(256) void gemm_nt(const float* __restrict__ A, int lda,
                                               const float* __restrict__ W, int ldw,
                                               const float* __restrict__ bias,
                                               float* __restrict__ C, int ldc,
                                               int M, int N, int K) {
  __shared__ float Asl[16][68];
  __shared__ float Wsl[16][68];
  int tid = threadIdx.x;
  int m0 = blockIdx.y * 64;
  int n0 = blockIdx.x * 64;
  int lrow = tid >> 2;
  int lq   = tid & 3;
  int tx = tid & 15;
  int ty = tid >> 4;
  float acc[4][4] = {{0.f}};

  for (int k0 = 0; k0 < K; k0 += 16) {
    float4 av = make_float4(0.f,0.f,0.f,0.f);
    int ar = m0 + lrow;
    if (ar < M) av = *(const float4*)(A + (size_t)ar*lda + k0 + lq*4);
    float4 wv = make_float4(0.f,0.f,0.f,0.f);
    int wr = n0 + lrow;
    if (wr < N) wv = *(const float4*)(W + (size_t)wr*ldw + k0 + lq*4);
    __syncthreads();
    Asl[lq*4+0][lrow] = av.x; Asl[lq*4+1][lrow] = av.y;
    Asl[lq*4+2][lrow] = av.z; Asl[lq*4+3][lrow] = av.w;
    Wsl[lq*4+0][lrow] = wv.x; Wsl[lq*4+1][lrow] = wv.y;
    Wsl[lq*4+2][lrow] = wv.z; Wsl[lq*4+3][lrow] = wv.w;
    __syncthreads();
#pragma unroll
    for (int kk = 0; kk < 16; ++kk) {
      float4 a4 = *(const float4*)&Asl[kk][ty*4];
      float4 w4 = *(const float4*)&Wsl[kk][tx*4];
      float a[4] = {a4.x, a4.y, a4.z, a4.w};
      float w[4] = {w4.x, w4.y, w4.z, w4.w};
#pragma unroll
      for (int i = 0; i < 4; ++i)
#pragma unroll
        for (int j = 0; j < 4; ++j)
          acc[i][j] += a[i]*w[j];
    }
  }

#pragma unroll
  for (int i = 0; i < 4; ++i) {
    int m = m0 + ty*4 + i;
    if (m >= M) continue;
    float* crow = C + (size_t)m*ldc;
    float bm = (ACT == 2) ? bias[m] : 0.f;
#pragma unroll
    for (int j = 0; j < 4; ++j) {
      int n = n0 + tx*4 + j;
      if (n >= N) continue;
      float val = acc[i][j];
      if (ACT == 2) {
        val += bm;
        val = (val > 20.f) ? val : log1pf(__expf(val));
      }
      crow[n] = val;
    }
  }
}

// ---------------- conv(4)+SiLU: writes ucq[tok][ch] (bf16) + uT[ch][tok] (f32) ----------------
// block: 64 ch x 64 tok tile. grid (DINNER/64, SEQL/64, BATCH)
__global__ __launch_bounds__(256) void conv_silu_kernel(const float* __restrict__ xz,
                                                        const float* __restrict__ conv_w,
                                                        const float* __restrict__ conv_b,
                                                        float* __restrict__ uT,
                                                        short* __restrict__ ucq) {
  __shared__ float tile[64][65];
  int b  = blockIdx.z;
  int c0 = blockIdx.x * 64;
  int t0 = blockIdx.y * 64;
  int lx = threadIdx.x & 63;       // channel local (read phase)
  int ly = threadIdx.x >> 6;       // 0..3
  int c = c0 + lx;
  const int S = 2*DINNER;
  float w0 = conv_w[c*4+0], w1 = conv_w[c*4+1], w2 = conv_w[c*4+2], w3 = conv_w[c*4+3];
  float cb = conv_b[c];
#pragma unroll
  for (int i = 0; i < 16; ++i) {
    int tl = ly*16 + i;
    int t = t0 + tl;
    const float* up = xz + ((size_t)b*SEQL + t) * S + c;
    float acc = cb + up[0]*w3;
    if (t >= 1) acc += up[-1*S]*w2;
    if (t >= 2) acc += up[-2*S]*w1;
    if (t >= 3) acc += up[-3*S]*w0;
    float sig = 1.f / (1.f + __expf(-acc));
    float v = acc * sig;
    ucq[((size_t)b*SEQL + t)*DINNER + c] = f2bf(v);
    tile[lx][tl] = v;
  }
  __syncthreads();
  // write uT[ch][tok] coalesced along tok: thread lx = token local now
#pragma unroll
  for (int i = 0; i < 16; ++i) {
    int cl = ly*16 + i;
    uT[((size_t)(c0 + cl))*NTOK + (size_t)b*SEQL + t0 + lx] = tile[cl][lx];
  }
}

__device__ inline float readlane_f(float v, int l) {
  return __int_as_float(__builtin_amdgcn_readlane(__float_as_int(v), l));
}

// ---------------- Selective scan v4 ----------------
// 4 channels/block (1 per wave, same batch). dT/uT coalesced [ch][tok].
// B/C cooperatively staged in LDS (shared by all 4 waves), 16-token double buffer.
__global__ __launch_bounds__(256) void scan_kernel(const float* __restrict__ dT,     // [DINNER... ch][NTOK]
                                                   const float* __restrict__ x_dbl,  // [NTOK][XDBL_P]
                                                   const float* __restrict__ uT,     // [ch][NTOK]
                                                   const float* __restrict__ A_log,  // [DINNER][64]
                                                   const float* __restrict__ Dp,     // [DINNER]
                                                   float* __restrict__ yT) {         // [B][DINNER][SEQL]
  __shared__ float bc[2][16*128];            // [buf][tok_local*128 + (B:0..63 | C:64..127)]
  __shared__ float red_all[4][32*65 + 32];
  int tid  = threadIdx.x;
  int wave = tid >> 6;
  int lane = tid & 63;
  float* red = red_all[wave];
  int ch = blockIdx.x * 4 + wave;            // 4 consecutive channels, same batch
  int b = ch / DINNER;
  int c = ch % DINNER;
  float Ac = -__expf(A_log[(size_t)c*64 + lane]);
  float Dc = Dp[c];
  float h = 0.f;
  const float* drow = dT + (size_t)ch * (SEQL);   // note: dT laid out [BATCH*DINNER? ] -> see launch (ldc=NTOK, ch*NTOK)
  // (actual pointers computed below with NTOK stride)
  const float* dp = dT + (size_t)c * NTOK + (size_t)b * SEQL;
  const float* up = uT + (size_t)c * NTOK + (size_t)b * SEQL;
  float* yrow = yT + ((size_t)b*DINNER + c) * SEQL;
  const float* xB = x_dbl + ((size_t)b * SEQL) * XDBL_P + DTRANK;   // [tok][128] B|C slice

  // staging thread roles: row = tid>>4 (16 rows), 8 floats at (tid&15)*8
  const int srow = tid >> 4, scol = (tid & 15) * 8;

  // prologue: stage group 0 (tokens 0..15)
  {
    const float* src = xB + (size_t)srow * XDBL_P + scol;
    float4 v0 = *(const float4*)(src);
    float4 v1 = *(const float4*)(src + 4);
    *(float4*)&bc[0][srow*128 + scol]     = v0;
    *(float4*)&bc[0][srow*128 + scol + 4] = v1;
  }
  // preload d/u for first 64-token block
  float d_v = dp[lane];
  float u_v = up[lane];
  __syncthreads();

  const int NBLK = SEQL/64;
  for (int tb = 0; tb < NBLK; ++tb) {
    int t0 = tb*64;
    float d_nxt = 0.f, u_nxt = 0.f;
    if (tb + 1 < NBLK) {
      d_nxt = dp[t0 + 64 + lane];
      u_nxt = up[t0 + 64 + lane];
    }
    float du_v = d_v * u_v;

#pragma unroll
    for (int g = 0; g < 4; ++g) {
      const int cur = g & 1;                 // global group G = tb*4+g, parity = g&1
      // issue next group's staging loads (tokens t0+(g+1)*16 .. +16)
      float4 rv0, rv1;
      bool do_stage = (tb*4 + g + 1) < 64;
      if (do_stage) {
        const float* src = xB + (size_t)(t0 + (g+1)*16 + srow) * XDBL_P + scol;
        rv0 = *(const float4*)(src);
        rv1 = *(const float4*)(src + 4);
      }
      // consume 16 tokens from bc[cur]
      const float* bcur = &bc[cur][0];
#pragma unroll
      for (int k = 0; k < 16; ++k) {
        int i = g*16 + k;
        float sd  = readlane_f(d_v,  i);
        float sdu = readlane_f(du_v, i);
        float Bv = bcur[k*128 + lane];
        float Cv = bcur[k*128 + 64 + lane];
        float dA = __expf(sd * Ac);
        h = fmaf(dA, h, sdu * Bv);
        red[(i & 31)*65 + lane] = h * Cv;
      }
      if (g & 1) {                           // reduce 32 tokens
        int half = g >> 1;
        int r  = lane & 31;
        int hs = lane >> 5;
        float y = 0.f;
        const float* rp = &red[r*65 + hs*32];
#pragma unroll
        for (int j = 0; j < 32; ++j) y += rp[j];
        y += __shfl_xor(y, 32);
        float ut = __shfl(u_v, half*32 + r);
        y = fmaf(Dc, ut, y);
        if (lane < 32) yrow[t0 + half*32 + lane] = y;
      }
      // write next group's stage into the other buffer (safe: others done reading it)
      if (do_stage) {
        *(float4*)&bc[cur^1][srow*128 + scol]     = rv0;
        *(float4*)&bc[cur^1][srow*128 + scol + 4] = rv1;
      }
      __syncthreads();
    }
    d_v = d_nxt;
    u_v = u_nxt;
  }
}

// ---------------- gate: g[b,t,c] = yT[b,c,t] * silu(z[b,t,c]) -> bf16 ----------------
__global__ __launch_bounds__(256) void ymul_kernel(const float* __restrict__ yT,
                                                   const float* __restrict__ xz,
                                                   short* __restrict__ g) {
  __shared__ float tile[64][65];
  int b  = blockIdx.z;
  int c0 = blockIdx.x * 64;
  int t0 = blockIdx.y * 64;
  int lx = threadIdx.x & 63;
  int ly = threadIdx.x >> 6;
  const float* src = yT + ((size_t)b*DINNER + c0) * SEQL + t0;
#pragma unroll
  for (int i = 0; i < 16; ++i) {
    int c = ly*16 + i;
    tile[c][lx] = src[(size_t)c*SEQL + lx];
  }
  __syncthreads();
  const int S = 2*DINNER;
#pragma unroll
  for (int i = 0; i < 16; ++i) {
    int t = ly*16 + i;
    float z = xz[((size_t)b*SEQL + t0 + t)*S + DINNER + c0 + lx];
    float zs = z / (1.f + __expf(-z));
    g[((size_t)b*SEQL + t0 + t)*DINNER + c0 + lx] = f2bf(tile[lx][t] * zs);
  }
}

extern "C" void kernel_launch(void* const* d_in, const int* in_sizes, int n_in,
                              void* d_out, int out_size, void* d_ws, size_t ws_size,
                              hipStream_t stream) {
  const float* x      = (const float*)d_in[0];
  const float* gamma  = (const float*)d_in[1];
  const float* beta   = (const float*)d_in[2];
  const float* W_in   = (const float*)d_in[3];
  const float* conv_w = (const float*)d_in[4];
  const float* conv_b = (const float*)d_in[5];
  const float* W_x    = (const float*)d_in[6];
  const float* W_dt   = (const float*)d_in[7];
  const float* b_dt   = (const float*)d_in[8];
  const float* A_log  = (const float*)d_in[9];
  const float* Dvec   = (const float*)d_in[10];
  const float* W_out  = (const float*)d_in[11];
  float* out = (float*)d_out;

  float* ws = (float*)d_ws;
  float* xz    = ws;                                  // NTOK*3072
  float* uT    = xz    + (size_t)NTOK*3072;           // DINNER*NTOK (f32, transposed)
  float* xdbl  = uT    + (size_t)NTOK*1536;           // NTOK*192
  float* dltT  = xdbl  + (size_t)NTOK*XDBL_P;         // DINNER*NTOK (transposed)
  float* yT    = dltT  + (size_t)NTOK*1536;           // NTOK*1536
  short* xnq   = (short*)(yT + (size_t)NTOK*1536);    // NTOK*768
  short* ucq   = xnq  + (size_t)NTOK*768;             // NTOK*1536
  short* gq    = ucq  + (size_t)NTOK*1536;            // NTOK*1536
  short* qin   = gq   + (size_t)NTOK*1536;            // 3072*768
  short* qx    = qin  + (size_t)NW_IN;                // 192*1536
  short* qout  = qx   + (size_t)NW_XP;                // 768*1536

  cvt_weights_kernel<<<(NW_IN+NW_OUT+NW_XP+255)/256, 256, 0, stream>>>(W_in, W_out, W_x, qin, qout, qx);
  ln_kernel<<<NTOK/4, 256, 0, stream>>>(x, gamma, beta, xnq);
  // xz = xn @ W_in^T  [2048 x 3072] bf16 MFMA
  gemm_mfma<128><<<dim3(3072/128, NTOK/128), 256, 0, stream>>>(xnq, qin, xz, 3072, DIMD);
  // conv + silu -> ucq [tok][ch] bf16, uT [ch][tok] f32
  conv_silu_kernel<<<dim3(DINNER/64, SEQL/64, BATCH), 256, 0, stream>>>(xz, conv_w, conv_b, uT, ucq);
  // x_dbl = uc @ W_x^T  [2048 x 192] bf16 MFMA
  gemm_mfma<64><<<dim3(XDBL_P/64, NTOK/128), 256, 0, stream>>>(ucq, qx, xdbl, XDBL_P, DINNER);
  // deltaT[ch][tok] = softplus(W_dt @ dt^T + b_dt[ch]):  M=1536(ch), N=2048(tok), K=48
  gemm_nt<2><<<dim3(NTOK/64, DINNER/64), 256, 0, stream>>>(W_dt, DTRANK, xdbl, XDBL_P, b_dt,
                                                           dltT, NTOK, DINNER, NTOK, DTRANK);
  // selective scan -> yT
  scan_kernel<<<BATCH*DINNER/4, 256, 0, stream>>>(dltT, xdbl, uT, A_log, Dvec, yT);
  // gate -> gq (bf16)
  ymul_kernel<<<dim3(DINNER/64, SEQL/64, BATCH), 256, 0, stream>>>(yT, xz, gq);
  // out = g @ W_out^T  [2048 x 768] bf16 MFMA
  gemm_mfma<64><<<dim3(DIMD/64, NTOK/128), 256, 0, stream>>>(gq, qout, out, DIMD, DINNER);
}